// Round 5
// baseline (844.794 us; speedup 1.0000x reference)
//
#include <hip/hip_runtime.h>

#define G 128
#define N 32
#define H 128
#define L 6

typedef _Float16 half8 __attribute__((ext_vector_type(8)));
typedef float f32x4 __attribute__((ext_vector_type(4)));

union H8 { unsigned u[4]; half8 v; };

__device__ inline unsigned short f16_bits(_Float16 h) {
  union { _Float16 f; unsigned short u; } c; c.f = h; return c.u;
}

// pack fp32 -> (f16 hi) | (f16 lo)<<16, hi = rne(x), lo = rne(x - hi)
__device__ inline unsigned packf16(float x) {
  _Float16 hi = (_Float16)x;
  _Float16 lo = (_Float16)(x - (float)hi);
  return (unsigned)f16_bits(hi) | ((unsigned)f16_bits(lo) << 16);
}

// ---------------------------------------------------------------------------
// E1: P0 = emb_x @ W0 + b0, P1 = emb_x @ W1 + b1. grid=2.
// ---------------------------------------------------------------------------
__global__ __launch_bounds__(256) void k_emb_mm(
    const float* __restrict__ emb_x,
    const float* __restrict__ W0, const float* __restrict__ b0, float* __restrict__ P0,
    const float* __restrict__ W1, const float* __restrict__ b1, float* __restrict__ P1) {
  const float* W = blockIdx.x ? W1 : W0;
  const float* b = blockIdx.x ? b1 : b0;
  float*       P = blockIdx.x ? P1 : P0;
  __shared__ float embs_t[128 * 32];   // [k][i]
  int tid = threadIdx.x;
  {
    int i = tid & 31, k0 = (tid >> 5) * 16;
    const float* src = emb_x + i * 128 + k0;
#pragma unroll
    for (int m = 0; m < 16; m++) embs_t[(k0 + m) * 32 + i] = src[m];
  }
  __syncthreads();
  int i  = tid >> 3;
  int h0 = (tid & 7) * 16;
  float acc[16];
#pragma unroll
  for (int hh = 0; hh < 16; hh++) acc[hh] = b[h0 + hh];
  for (int k = 0; k < 128; k++) {
    float a = embs_t[k * 32 + i];
    const float4* wr = (const float4*)(W + k * 128 + h0);
    float4 w0 = wr[0], w1 = wr[1], w2 = wr[2], w3 = wr[3];
    acc[0]  += a * w0.x; acc[1]  += a * w0.y; acc[2]  += a * w0.z; acc[3]  += a * w0.w;
    acc[4]  += a * w1.x; acc[5]  += a * w1.y; acc[6]  += a * w1.z; acc[7]  += a * w1.w;
    acc[8]  += a * w2.x; acc[9]  += a * w2.y; acc[10] += a * w2.z; acc[11] += a * w2.w;
    acc[12] += a * w3.x; acc[13] += a * w3.y; acc[14] += a * w3.z; acc[15] += a * w3.w;
  }
  float4* dst = (float4*)(P + i * 128 + h0);
  dst[0] = make_float4(acc[0], acc[1], acc[2], acc[3]);
  dst[1] = make_float4(acc[4], acc[5], acc[6], acc[7]);
  dst[2] = make_float4(acc[8], acc[9], acc[10], acc[11]);
  dst[3] = make_float4(acc[12], acc[13], acc[14], acc[15]);
}

// ---------------------------------------------------------------------------
// E2: build X h-planar: Xp[g][h][i*32+j]. One WG per graph.
// ---------------------------------------------------------------------------
__global__ __launch_bounds__(256) void k_buildX(
    const int* __restrict__ x_idx, const int* __restrict__ tf_idx,
    const float* __restrict__ P0, const float* __restrict__ P1,
    const float* __restrict__ emb_tf, float* __restrict__ Xp) {
  int g = blockIdx.x, tid = threadIdx.x;
  __shared__ float x0t[128 * 32];
  __shared__ float x1t[128 * 32];
  __shared__ float etf[128 * 16];
  __shared__ int   tfs[1024];
  {
    int i = tid & 31, h0 = (tid >> 5) * 16;
    int r = x_idx[g * 32 + i];
    const float* s0 = P0 + r * 128 + h0;
    const float* s1 = P1 + r * 128 + h0;
#pragma unroll
    for (int m = 0; m < 16; m++) {
      x0t[(h0 + m) * 32 + i] = s0[m];
      x1t[(h0 + m) * 32 + i] = s1[m];
    }
  }
  {
    int t = tid & 15, h0 = (tid >> 4) * 8;
    const float* s = emb_tf + t * 128 + h0;
#pragma unroll
    for (int m = 0; m < 8; m++) etf[(h0 + m) * 16 + t] = s[m];
  }
  ((int4*)tfs)[tid] = ((const int4*)(tf_idx + (size_t)g * 1024))[tid];
  __syncthreads();
  int i = tid >> 3, j0 = (tid & 7) * 4;
  int t0 = tfs[i * 32 + j0 + 0], t1 = tfs[i * 32 + j0 + 1];
  int t2 = tfs[i * 32 + j0 + 2], t3 = tfs[i * 32 + j0 + 3];
  float* outg = Xp + ((size_t)g << 17);
  for (int h = 0; h < 128; h++) {
    float a = x0t[h * 32 + i];
    const float* x1r = x1t + h * 32;
    const float* er  = etf + h * 16;
    float4 v;
    v.x = a * x1r[j0 + 0] * er[t0];
    v.y = a * x1r[j0 + 1] * er[t1];
    v.z = a * x1r[j0 + 2] * er[t2];
    v.w = a * x1r[j0 + 3] * er[t3];
    *(float4*)(outg + h * 1024 + tid * 4) = v;
  }
}

// ---------------------------------------------------------------------------
// PW: pre-pack Wc as f16 hi/lo pair planes, transposed for fragment loads.
// Whi[l][h][kp] = f16hi(W[l][2kp][h]) | f16hi(W[l][2kp+1][h])<<16, Wlo same
// with the lo halves. One-time per launch; 6x64KB. grid=192.
// ---------------------------------------------------------------------------
__global__ __launch_bounds__(256) void k_packW(
    const float* __restrict__ Wc, unsigned* __restrict__ Whi,
    unsigned* __restrict__ Wlo) {
  int o  = blockIdx.x * 256 + threadIdx.x;      // 0 .. 49151
  int kp = o & 63;
  int h  = (o >> 6) & 127;
  int l  = o >> 13;
  const float* Wl = Wc + (size_t)l * 16384;
  float a = Wl[(2 * kp) * 128 + h];
  float b = Wl[(2 * kp + 1) * 128 + h];
  unsigned pa = packf16(a), pb = packf16(b);
  Whi[o] = __builtin_amdgcn_perm(pb, pa, 0x05040100u);
  Wlo[o] = __builtin_amdgcn_perm(pb, pa, 0x07060302u);
}

// ---------------------------------------------------------------------------
// K1 v7 (MFMA, LDS tile, coalesced in AND out): tXp = relu(LN(X@Wc+bc)).
// Same math/values as v5 (packf16 + 3x mfma_16x16x32_f16 hi/lo, same order)
// -> identical results. Structure: one 34 KB LDS tile T (stride-66 rows,
// ~2-way banking = free):
//   phase 1: stage X[k=0..127][p-range 64] via fully-coalesced float4 loads
//            (8 concurrent/thread -> single latency exposure, 256B segments)
//   phase 2: B-frags from LDS scalars, A-frags from packed Whi/Wlo (L2),
//            96 MFMA/wave
//   phase 3: LN, then acc -> T[h][p] transpose
//   phase 4: fully-coalesced float4 stores, 256B segments per h-plane
// grid = G*16 (64 p per WG, 1 p-tile/wave), 4 WGs/CU resident.
// ---------------------------------------------------------------------------
__global__ __launch_bounds__(256, 4) void k_conv_mlp(
    const float* __restrict__ Xp, const unsigned* __restrict__ Whi,
    const unsigned* __restrict__ Wlo,
    const float* __restrict__ bcl, const float* __restrict__ gcl,
    const float* __restrict__ ccl, float* __restrict__ tXp) {
  int g = blockIdx.x >> 4, qb = blockIdx.x & 15;
  int tid = threadIdx.x;
  int lane = tid & 63, wv = tid >> 6;
  int x = lane & 15, quad = lane >> 4;
  __shared__ float T[128 * 66];   // in: X[k][p]; out: Y[h][p] (stride 66)

  // ---- accumulator init with bias bc[h], h = hh*16 + quad*4 + r
  f32x4 acc[8];
#pragma unroll
  for (int hh = 0; hh < 8; hh++) {
    float4 b4 = *(const float4*)(bcl + hh * 16 + quad * 4);
    f32x4 bi; bi[0] = b4.x; bi[1] = b4.y; bi[2] = b4.z; bi[3] = b4.w;
    acc[hh] = bi;
  }

  // ---- phase 1: stage input tile (coalesced float4, 8 in flight)
  {
    const float* Xg = Xp + ((size_t)g << 17) + qb * 64;
#pragma unroll
    for (int m = 0; m < 8; m++) {
      int f = m * 256 + tid;               // 0..2047
      int k = f >> 4, p4 = (f & 15) * 4;
      float4 v = *(const float4*)(Xg + ((size_t)k << 10) + p4);
      float* d = &T[k * 66 + p4];
      *(float2*)(d)     = make_float2(v.x, v.y);
      *(float2*)(d + 2) = make_float2(v.z, v.w);
    }
  }
  __syncthreads();

  // ---- phase 2: MFMA over 4 k-chunks
  for (int c = 0; c < 4; c++) {
    // B fragment pair from LDS (p = wv*16 + x)
    unsigned pk[8];
#pragma unroll
    for (int j = 0; j < 8; j++)
      pk[j] = packf16(T[(c * 32 + quad * 8 + j) * 66 + wv * 16 + x]);
    H8 bh, bl;
#pragma unroll
    for (int n = 0; n < 4; n++) {
      bh.u[n] = __builtin_amdgcn_perm(pk[2 * n + 1], pk[2 * n], 0x05040100u);
      bl.u[n] = __builtin_amdgcn_perm(pk[2 * n + 1], pk[2 * n], 0x07060302u);
    }
    // stream A pairs over 8 h-tiles, 3 MFMA per tile
#pragma unroll
    for (int hh = 0; hh < 8; hh++) {
      int hrow = hh * 16 + x;
      H8 ah, al;
      *(uint4*)&ah.u[0] = *(const uint4*)(Whi + (size_t)hrow * 64 + c * 16 + quad * 4);
      *(uint4*)&al.u[0] = *(const uint4*)(Wlo + (size_t)hrow * 64 + c * 16 + quad * 4);
      acc[hh] = __builtin_amdgcn_mfma_f32_16x16x32_f16(ah.v, bh.v, acc[hh], 0, 0, 0);
      acc[hh] = __builtin_amdgcn_mfma_f32_16x16x32_f16(ah.v, bl.v, acc[hh], 0, 0, 0);
      acc[hh] = __builtin_amdgcn_mfma_f32_16x16x32_f16(al.v, bh.v, acc[hh], 0, 0, 0);
    }
  }
  __syncthreads();   // all fragment reads of T complete before overwrite

  // ---- phase 3: LN over h (in registers + quad butterflies), write T[h][p]
  {
    float s = 0.f;
#pragma unroll
    for (int hh = 0; hh < 8; hh++)
#pragma unroll
      for (int r = 0; r < 4; r++) s += acc[hh][r];
    s += __shfl_xor(s, 16);
    s += __shfl_xor(s, 32);
    float m = s * (1.f / 128.f);
    float qv = 0.f;
#pragma unroll
    for (int hh = 0; hh < 8; hh++)
#pragma unroll
      for (int r = 0; r < 4; r++) { float d = acc[hh][r] - m; qv += d * d; }
    qv += __shfl_xor(qv, 16);
    qv += __shfl_xor(qv, 32);
    float gr = rsqrtf(qv * (1.f / 128.f) + 1e-5f);
#pragma unroll
    for (int hh = 0; hh < 8; hh++) {
      float4 g4 = *(const float4*)(gcl + hh * 16 + quad * 4);
      float4 c4 = *(const float4*)(ccl + hh * 16 + quad * 4);
      float ga[4] = {g4.x, g4.y, g4.z, g4.w};
      float ca[4] = {c4.x, c4.y, c4.z, c4.w};
#pragma unroll
      for (int r = 0; r < 4; r++) {
        float v = (acc[hh][r] - m) * gr * ga[r] + ca[r];
        T[(hh * 16 + quad * 4 + r) * 66 + wv * 16 + x] = fmaxf(v, 0.f);
      }
    }
  }
  __syncthreads();

  // ---- phase 4: coalesced stores (256B segments per h-plane)
  {
    float* outg = tXp + (((size_t)g * 128) << 10) + qb * 64;
#pragma unroll
    for (int m = 0; m < 8; m++) {
      int rid = m * 256 + tid;             // 0..2047
      int h = rid >> 4, p4 = (rid & 15) * 4;
      const float* src = &T[h * 66 + p4];
      float2 a = *(const float2*)(src);
      float2 b = *(const float2*)(src + 2);
      *(float4*)(outg + ((size_t)h << 10) + p4) = make_float4(a.x, a.y, b.x, b.y);
    }
  }
}

// ---------------------------------------------------------------------------
// K2 v5: X[g,h,i,j] += sum_k tX * A. 8 h-planes per WG (grid G*16), 2 per
// wave; A from packed codes; 4x4 lane tile. POOL is a TEMPLATE parameter so
// the POOL=0 instantiation's codegen is identical to the verified original.
// POOL=1 (final layer): reduce each row i over j and write only the 32
// row-means into Xp[g][h][0..31] (plane exclusively owned by this wave;
// loads precede the store -> race-free). Saves the 64 MB write-back.
// ---------------------------------------------------------------------------
template <int POOL>
__global__ __launch_bounds__(256, 4) void k_conv_msg(
    const float* __restrict__ tXp, const int* __restrict__ ea_idx,
    const int* __restrict__ adj, const float* __restrict__ emb_ea,
    float* __restrict__ Xp) {
  int g  = blockIdx.x >> 4;
  int hb = (blockIdx.x & 15) * 8;
  int tid = threadIdx.x, wv = tid >> 6, lane = tid & 63;
  __shared__ unsigned char c8[1024];
  __shared__ float eacs[8][20];
  __shared__ __align__(16) float tXs[4][32 * 36];
  __shared__ __align__(16) float As[4][32 * 36];
  {
    int4 ev = ((const int4*)(ea_idx + (size_t)g * 1024))[tid];
    int4 av = ((const int4*)(adj   + (size_t)g * 1024))[tid];
    uchar4 c;
    c.x = av.x ? (unsigned char)ev.x : (unsigned char)16;
    c.y = av.y ? (unsigned char)ev.y : (unsigned char)16;
    c.z = av.z ? (unsigned char)ev.z : (unsigned char)16;
    c.w = av.w ? (unsigned char)ev.w : (unsigned char)16;
    ((uchar4*)c8)[tid] = c;
  }
  if (tid < 128) {
    int hh = tid >> 4, e = tid & 15;
    eacs[hh][e] = emb_ea[e * 128 + hb + hh];
  }
  if (tid >= 128 && tid < 136) eacs[tid - 128][16] = 0.f;
  __syncthreads();
  int i0 = (lane >> 3) * 4, j0 = (lane & 7) * 4;
  float* tw = tXs[wv];
  float* aw = As[wv];
#pragma unroll 1
  for (int pl = 0; pl < 2; pl++) {
    int hh = wv * 2 + pl;
    int h  = hb + hh;
    const float4* tp = (const float4*)(tXp + (((size_t)(g * 128 + h)) << 10));
#pragma unroll
    for (int m = 0; m < 4; m++) {
      int f = lane + 64 * m;
      float4 v = tp[f];
      *(float4*)&tw[(f >> 3) * 36 + (f & 7) * 4] = v;
    }
#pragma unroll
    for (int m = 0; m < 4; m++) {
      int qd = lane + 64 * m;
      uchar4 cc = ((const uchar4*)c8)[qd];
      float4 a;
      a.x = eacs[hh][cc.x]; a.y = eacs[hh][cc.y];
      a.z = eacs[hh][cc.z]; a.w = eacs[hh][cc.w];
      *(float4*)&aw[(qd >> 3) * 36 + (qd & 7) * 4] = a;
    }
    float4 a0 = {0, 0, 0, 0}, a1 = a0, a2 = a0, a3 = a0;
#pragma unroll
    for (int kb = 0; kb < 8; kb++) {
      int k4 = kb * 4;
      float4 t0 = *(const float4*)&tw[(i0 + 0) * 36 + k4];
      float4 t1 = *(const float4*)&tw[(i0 + 1) * 36 + k4];
      float4 t2 = *(const float4*)&tw[(i0 + 2) * 36 + k4];
      float4 t3 = *(const float4*)&tw[(i0 + 3) * 36 + k4];
      float4 b0 = *(const float4*)&aw[(k4 + 0) * 36 + j0];
      float4 b1 = *(const float4*)&aw[(k4 + 1) * 36 + j0];
      float4 b2 = *(const float4*)&aw[(k4 + 2) * 36 + j0];
      float4 b3 = *(const float4*)&aw[(k4 + 3) * 36 + j0];
      a0.x += t0.x * b0.x; a0.y += t0.x * b0.y; a0.z += t0.x * b0.z; a0.w += t0.x * b0.w;
      a0.x += t0.y * b1.x; a0.y += t0.y * b1.y; a0.z += t0.y * b1.z; a0.w += t0.y * b1.w;
      a0.x += t0.z * b2.x; a0.y += t0.z * b2.y; a0.z += t0.z * b2.z; a0.w += t0.z * b2.w;
      a0.x += t0.w * b3.x; a0.y += t0.w * b3.y; a0.z += t0.w * b3.z; a0.w += t0.w * b3.w;
      a1.x += t1.x * b0.x; a1.y += t1.x * b0.y; a1.z += t1.x * b0.z; a1.w += t1.x * b0.w;
      a1.x += t1.y * b1.x; a1.y += t1.y * b1.y; a1.z += t1.y * b1.z; a1.w += t1.y * b1.w;
      a1.x += t1.z * b2.x; a1.y += t1.z * b2.y; a1.z += t1.z * b2.z; a1.w += t1.z * b2.w;
      a1.x += t1.w * b3.x; a1.y += t1.w * b3.y; a1.z += t1.w * b3.z; a1.w += t1.w * b3.w;
      a2.x += t2.x * b0.x; a2.y += t2.x * b0.y; a2.z += t2.x * b0.z; a2.w += t2.x * b0.w;
      a2.x += t2.y * b1.x; a2.y += t2.y * b1.y; a2.z += t2.y * b1.z; a2.w += t2.y * b1.w;
      a2.x += t2.z * b2.x; a2.y += t2.z * b2.y; a2.z += t2.z * b2.z; a2.w += t2.z * b2.w;
      a2.x += t2.w * b3.x; a2.y += t2.w * b3.y; a2.z += t2.w * b3.z; a2.w += t2.w * b3.w;
      a3.x += t3.x * b0.x; a3.y += t3.x * b0.y; a3.z += t3.x * b0.z; a3.w += t3.x * b0.w;
      a3.x += t3.y * b1.x; a3.y += t3.y * b1.y; a3.z += t3.y * b1.z; a3.w += t3.y * b1.w;
      a3.x += t3.z * b2.x; a3.y += t3.z * b2.y; a3.z += t3.z * b2.z; a3.w += t3.z * b2.w;
      a3.x += t3.w * b3.x; a3.y += t3.w * b3.y; a3.z += t3.w * b3.z; a3.w += t3.w * b3.w;
    }
    float* xr = Xp + (((size_t)(g * 128 + h)) << 10);
    float4* r0 = (float4*)&xr[(i0 + 0) * 32 + j0];
    float4* r1 = (float4*)&xr[(i0 + 1) * 32 + j0];
    float4* r2 = (float4*)&xr[(i0 + 2) * 32 + j0];
    float4* r3 = (float4*)&xr[(i0 + 3) * 32 + j0];
    float4 x0 = *r0, x1 = *r1, x2 = *r2, x3 = *r3;
    x0.x += a0.x; x0.y += a0.y; x0.z += a0.z; x0.w += a0.w;
    x1.x += a1.x; x1.y += a1.y; x1.z += a1.z; x1.w += a1.w;
    x2.x += a2.x; x2.y += a2.y; x2.z += a2.z; x2.w += a2.w;
    x3.x += a3.x; x3.y += a3.y; x3.z += a3.z; x3.w += a3.w;
    if (!POOL) {
      *r0 = x0; *r1 = x1; *r2 = x2; *r3 = x3;
    } else {
      // mean over j of the updated rows; write 32 means into plane[0..31]
      float s0 = x0.x + x0.y + x0.z + x0.w;
      float s1 = x1.x + x1.y + x1.z + x1.w;
      float s2 = x2.x + x2.y + x2.z + x2.w;
      float s3 = x3.x + x3.y + x3.z + x3.w;
      s0 += __shfl_xor(s0, 1); s0 += __shfl_xor(s0, 2); s0 += __shfl_xor(s0, 4);
      s1 += __shfl_xor(s1, 1); s1 += __shfl_xor(s1, 2); s1 += __shfl_xor(s1, 4);
      s2 += __shfl_xor(s2, 1); s2 += __shfl_xor(s2, 2); s2 += __shfl_xor(s2, 4);
      s3 += __shfl_xor(s3, 1); s3 += __shfl_xor(s3, 2); s3 += __shfl_xor(s3, 4);
      if ((lane & 7) == 0) {
        float4 v = make_float4(s0 * 0.03125f, s1 * 0.03125f,
                               s2 * 0.03125f, s3 * 0.03125f);
        *(float4*)&xr[i0] = v;
      }
    }
  }
}

// ---------------------------------------------------------------------------
// T v2: reads pooled means xs[g][h][i] from Xp plane heads (written by the
// final k_conv_msg<1>). -> @Wp+bp -> rowLN(registers+shfl) -> relu
// -> sum over i -> @Wq1+bq1 -> LN(wave reduce) -> relu -> @Wq2+bq2.
// ---------------------------------------------------------------------------
__global__ __launch_bounds__(256) void k_tail(
    const float* __restrict__ Xp,
    const float* __restrict__ Wp, const float* __restrict__ bp,
    const float* __restrict__ gp, const float* __restrict__ cp,
    const float* __restrict__ Wq1, const float* __restrict__ bq1,
    const float* __restrict__ gq1, const float* __restrict__ cq1,
    const float* __restrict__ Wq2, const float* __restrict__ bq2,
    float* __restrict__ out) {
  int g = blockIdx.x, tid = threadIdx.x;
  __shared__ float xs_s[32 * 132];
  __shared__ float y_s[32 * 132];
  __shared__ float stat_m[1], stat_r[1];
  __shared__ float hg_s[128];
  __shared__ float q_s[128];
  __shared__ float redf[128];
  const float* Xg = Xp + ((size_t)g << 17);
  {
    // load pooled means: Xg[h*1024 + i], i<32 -> xs_s[i*132 + h]
    int h = tid >> 1, i0 = (tid & 1) * 16;
    const float4* src = (const float4*)(Xg + (size_t)h * 1024 + i0);
    float4 v0 = src[0], v1 = src[1], v2 = src[2], v3 = src[3];
    xs_s[(i0 +  0) * 132 + h] = v0.x; xs_s[(i0 +  1) * 132 + h] = v0.y;
    xs_s[(i0 +  2) * 132 + h] = v0.z; xs_s[(i0 +  3) * 132 + h] = v0.w;
    xs_s[(i0 +  4) * 132 + h] = v1.x; xs_s[(i0 +  5) * 132 + h] = v1.y;
    xs_s[(i0 +  6) * 132 + h] = v1.z; xs_s[(i0 +  7) * 132 + h] = v1.w;
    xs_s[(i0 +  8) * 132 + h] = v2.x; xs_s[(i0 +  9) * 132 + h] = v2.y;
    xs_s[(i0 + 10) * 132 + h] = v2.z; xs_s[(i0 + 11) * 132 + h] = v2.w;
    xs_s[(i0 + 12) * 132 + h] = v3.x; xs_s[(i0 + 13) * 132 + h] = v3.y;
    xs_s[(i0 + 14) * 132 + h] = v3.z; xs_s[(i0 + 15) * 132 + h] = v3.w;
  }
  __syncthreads();
  int i_ = tid >> 3, h0 = (tid & 7) * 16;
  float acc[16];
#pragma unroll
  for (int hh = 0; hh < 16; hh++) acc[hh] = bp[h0 + hh];
  for (int k = 0; k < 128; k++) {
    float a = xs_s[i_ * 132 + k];
    const float4* wr = (const float4*)(Wp + k * 128 + h0);
    float4 w0 = wr[0], w1 = wr[1], w2 = wr[2], w3 = wr[3];
    acc[0]  += a * w0.x; acc[1]  += a * w0.y; acc[2]  += a * w0.z; acc[3]  += a * w0.w;
    acc[4]  += a * w1.x; acc[5]  += a * w1.y; acc[6]  += a * w1.z; acc[7]  += a * w1.w;
    acc[8]  += a * w2.x; acc[9]  += a * w2.y; acc[10] += a * w2.z; acc[11] += a * w2.w;
    acc[12] += a * w3.x; acc[13] += a * w3.y; acc[14] += a * w3.z; acc[15] += a * w3.w;
  }
  // ---- row LN in registers: 8 threads per row, shfl butterflies ----
  {
    float s = 0.f;
#pragma unroll
    for (int hh = 0; hh < 16; hh++) s += acc[hh];
    s += __shfl_xor(s, 1); s += __shfl_xor(s, 2); s += __shfl_xor(s, 4);
    float m = s * (1.f / 128.f);
    float qv = 0.f;
#pragma unroll
    for (int hh = 0; hh < 16; hh++) { float d = acc[hh] - m; qv += d * d; }
    qv += __shfl_xor(qv, 1); qv += __shfl_xor(qv, 2); qv += __shfl_xor(qv, 4);
    float r = rsqrtf(qv * (1.f / 128.f) + 1e-5f);
#pragma unroll
    for (int hh = 0; hh < 16; hh++) {
      int hc = h0 + hh;
      float v = (acc[hh] - m) * r * gp[hc] + cp[hc];
      y_s[i_ * 132 + hc] = fmaxf(v, 0.f);
    }
  }
  __syncthreads();
  if (tid < 128) {
    float s = 0.f;
#pragma unroll
    for (int ii = 0; ii < 32; ii++) s += y_s[ii * 132 + tid];
    hg_s[tid] = s;
  }
  __syncthreads();
  if (tid < 128) {
    float a = bq1[tid];
    for (int k = 0; k < 128; k++) a += hg_s[k] * Wq1[k * 128 + tid];
    q_s[tid] = a;
  }
  __syncthreads();
  if (tid < 64) {
    float a = q_s[tid], b = q_s[tid + 64];
    float s = a + b;
#pragma unroll
    for (int o = 1; o < 64; o <<= 1) s += __shfl_xor(s, o);
    float m = s * (1.f / 128.f);
    float d1 = a - m, d2 = b - m;
    float qq = d1 * d1 + d2 * d2;
#pragma unroll
    for (int o = 1; o < 64; o <<= 1) qq += __shfl_xor(qq, o);
    if (tid == 0) { stat_m[0] = m; stat_r[0] = rsqrtf(qq * (1.f / 128.f) + 1e-5f); }
  }
  __syncthreads();
  if (tid < 128) {
    float v = (q_s[tid] - stat_m[0]) * stat_r[0] * gq1[tid] + cq1[tid];
    v = fmaxf(v, 0.f);
    redf[tid] = v * Wq2[tid];
  }
  __syncthreads();
  if (tid < 64) {
    float s = redf[tid] + redf[tid + 64];
#pragma unroll
    for (int o = 1; o < 64; o <<= 1) s += __shfl_xor(s, o);
    if (tid == 0) out[g] = s + bq2[0];
  }
}

// ---------------------------------------------------------------------------
extern "C" void kernel_launch(void* const* d_in, const int* in_sizes, int n_in,
                              void* d_out, int out_size, void* d_ws, size_t ws_size,
                              hipStream_t stream) {
  const int*   x_idx  = (const int*)d_in[0];
  const int*   ea_idx = (const int*)d_in[1];
  const int*   tf_idx = (const int*)d_in[2];
  const int*   adj    = (const int*)d_in[3];
  const float* emb_x  = (const float*)d_in[4];
  const float* emb_ea = (const float*)d_in[5];
  const float* emb_tf = (const float*)d_in[6];
  const float* W0  = (const float*)d_in[7];
  const float* b0  = (const float*)d_in[8];
  const float* W1  = (const float*)d_in[9];
  const float* b1  = (const float*)d_in[10];
  const float* Wc  = (const float*)d_in[11];
  const float* bc  = (const float*)d_in[12];
  const float* gc  = (const float*)d_in[13];
  const float* cc  = (const float*)d_in[14];
  const float* Wp  = (const float*)d_in[15];
  const float* bp  = (const float*)d_in[16];
  const float* gp  = (const float*)d_in[17];
  const float* cp  = (const float*)d_in[18];
  const float* Wq1 = (const float*)d_in[19];
  const float* bq1 = (const float*)d_in[20];
  const float* gq1 = (const float*)d_in[21];
  const float* cq1 = (const float*)d_in[22];
  const float* Wq2 = (const float*)d_in[23];
  const float* bq2 = (const float*)d_in[24];
  float* out = (float*)d_out;

  float* ws  = (float*)d_ws;
  float* Xp  = ws;
  float* tXp = ws + (size_t)16777216;
  float* P0  = ws + (size_t)33554432;
  float* P1  = P0 + 4096;
  unsigned* Whi = (unsigned*)(ws + (size_t)33562624);  // 6*128*64 u32
  unsigned* Wlo = Whi + 49152;

  k_emb_mm<<<2, 256, 0, stream>>>(emb_x, W0, b0, P0, W1, b1, P1);
  k_packW<<<192, 256, 0, stream>>>(Wc, Whi, Wlo);
  k_buildX<<<G, 256, 0, stream>>>(x_idx, tf_idx, P0, P1, emb_tf, Xp);
  for (int l = 0; l < L; l++) {
    k_conv_mlp<<<G * 16, 256, 0, stream>>>(Xp, Whi + (size_t)l * 8192,
                                           Wlo + (size_t)l * 8192,
                                           bc + l * H, gc + l * H, cc + l * H, tXp);
    if (l == L - 1)
      k_conv_msg<1><<<G * 16, 256, 0, stream>>>(tXp, ea_idx, adj, emb_ea, Xp);
    else
      k_conv_msg<0><<<G * 16, 256, 0, stream>>>(tXp, ea_idx, adj, emb_ea, Xp);
  }
  k_tail<<<G, 256, 0, stream>>>(Xp, Wp, bp, gp, cp, Wq1, bq1, gq1, cq1, Wq2, bq2, out);
}

// Round 6
// 592.295 us; speedup vs baseline: 1.4263x; 1.4263x over previous
//
#include <hip/hip_runtime.h>

#define G 128
#define N 32
#define H 128
#define L 6

typedef _Float16 half8 __attribute__((ext_vector_type(8)));
typedef float f32x4 __attribute__((ext_vector_type(4)));

union H8 { unsigned u[4]; half8 v; };

__device__ inline unsigned short f16_bits(_Float16 h) {
  union { _Float16 f; unsigned short u; } c; c.f = h; return c.u;
}

// pack fp32 -> (f16 hi) | (f16 lo)<<16, hi = rne(x), lo = rne(x - hi)
__device__ inline unsigned packf16(float x) {
  _Float16 hi = (_Float16)x;
  _Float16 lo = (_Float16)(x - (float)hi);
  return (unsigned)f16_bits(hi) | ((unsigned)f16_bits(lo) << 16);
}

// ---------------------------------------------------------------------------
// E1: P0 = emb_x @ W0 + b0, P1 = emb_x @ W1 + b1. grid=2.
// ---------------------------------------------------------------------------
__global__ __launch_bounds__(256) void k_emb_mm(
    const float* __restrict__ emb_x,
    const float* __restrict__ W0, const float* __restrict__ b0, float* __restrict__ P0,
    const float* __restrict__ W1, const float* __restrict__ b1, float* __restrict__ P1) {
  const float* W = blockIdx.x ? W1 : W0;
  const float* b = blockIdx.x ? b1 : b0;
  float*       P = blockIdx.x ? P1 : P0;
  __shared__ float embs_t[128 * 32];   // [k][i]
  int tid = threadIdx.x;
  {
    int i = tid & 31, k0 = (tid >> 5) * 16;
    const float* src = emb_x + i * 128 + k0;
#pragma unroll
    for (int m = 0; m < 16; m++) embs_t[(k0 + m) * 32 + i] = src[m];
  }
  __syncthreads();
  int i  = tid >> 3;
  int h0 = (tid & 7) * 16;
  float acc[16];
#pragma unroll
  for (int hh = 0; hh < 16; hh++) acc[hh] = b[h0 + hh];
  for (int k = 0; k < 128; k++) {
    float a = embs_t[k * 32 + i];
    const float4* wr = (const float4*)(W + k * 128 + h0);
    float4 w0 = wr[0], w1 = wr[1], w2 = wr[2], w3 = wr[3];
    acc[0]  += a * w0.x; acc[1]  += a * w0.y; acc[2]  += a * w0.z; acc[3]  += a * w0.w;
    acc[4]  += a * w1.x; acc[5]  += a * w1.y; acc[6]  += a * w1.z; acc[7]  += a * w1.w;
    acc[8]  += a * w2.x; acc[9]  += a * w2.y; acc[10] += a * w2.z; acc[11] += a * w2.w;
    acc[12] += a * w3.x; acc[13] += a * w3.y; acc[14] += a * w3.z; acc[15] += a * w3.w;
  }
  float4* dst = (float4*)(P + i * 128 + h0);
  dst[0] = make_float4(acc[0], acc[1], acc[2], acc[3]);
  dst[1] = make_float4(acc[4], acc[5], acc[6], acc[7]);
  dst[2] = make_float4(acc[8], acc[9], acc[10], acc[11]);
  dst[3] = make_float4(acc[12], acc[13], acc[14], acc[15]);
}

// ---------------------------------------------------------------------------
// E2: build X h-planar: Xp[g][h][i*32+j]. One WG per graph.
// ---------------------------------------------------------------------------
__global__ __launch_bounds__(256) void k_buildX(
    const int* __restrict__ x_idx, const int* __restrict__ tf_idx,
    const float* __restrict__ P0, const float* __restrict__ P1,
    const float* __restrict__ emb_tf, float* __restrict__ Xp) {
  int g = blockIdx.x, tid = threadIdx.x;
  __shared__ float x0t[128 * 32];
  __shared__ float x1t[128 * 32];
  __shared__ float etf[128 * 16];
  __shared__ int   tfs[1024];
  {
    int i = tid & 31, h0 = (tid >> 5) * 16;
    int r = x_idx[g * 32 + i];
    const float* s0 = P0 + r * 128 + h0;
    const float* s1 = P1 + r * 128 + h0;
#pragma unroll
    for (int m = 0; m < 16; m++) {
      x0t[(h0 + m) * 32 + i] = s0[m];
      x1t[(h0 + m) * 32 + i] = s1[m];
    }
  }
  {
    int t = tid & 15, h0 = (tid >> 4) * 8;
    const float* s = emb_tf + t * 128 + h0;
#pragma unroll
    for (int m = 0; m < 8; m++) etf[(h0 + m) * 16 + t] = s[m];
  }
  ((int4*)tfs)[tid] = ((const int4*)(tf_idx + (size_t)g * 1024))[tid];
  __syncthreads();
  int i = tid >> 3, j0 = (tid & 7) * 4;
  int t0 = tfs[i * 32 + j0 + 0], t1 = tfs[i * 32 + j0 + 1];
  int t2 = tfs[i * 32 + j0 + 2], t3 = tfs[i * 32 + j0 + 3];
  float* outg = Xp + ((size_t)g << 17);
  for (int h = 0; h < 128; h++) {
    float a = x0t[h * 32 + i];
    const float* x1r = x1t + h * 32;
    const float* er  = etf + h * 16;
    float4 v;
    v.x = a * x1r[j0 + 0] * er[t0];
    v.y = a * x1r[j0 + 1] * er[t1];
    v.z = a * x1r[j0 + 2] * er[t2];
    v.w = a * x1r[j0 + 3] * er[t3];
    *(float4*)(outg + h * 1024 + tid * 4) = v;
  }
}

// ---------------------------------------------------------------------------
// KF (fused conv layer): one WG per (g, i-octet). grid = G*4, 256 threads.
// p-slab = oct*256 .. +256 = i-rows [oct*8, oct*8+8) x all k. The msg
// contraction over k needs Y only from the WG's own slab, LN is p-row-local,
// and the residual touches only the slab -> ZERO cross-WG exchange, X
// updated IN PLACE (slabs disjoint). tXp eliminated.
//   phase A: v4's verified MFMA mlp (f16 hi/lo, 3x mfma per tile, LDS
//            chunk staging with XOR swizzle) -> acc = X@W + b
//   phase B: LN + relu in registers (v4's butterflies), acc := Y
//   phase C: 4 rounds x { deposit Y 32-plane quarter to LDS; barrier;
//            per-wave 8 planes: A from codes+eacs (msg-v5 staging),
//            Yh(8x32) @ Ah(32x32) FMA (identical k-order to msg-v5),
//            residual add, in-place store (or POOL: row-mean -> Pm) }
// LDS: union(Xs+Ws 48K, Ys 36.5K) + aw 18K + codes 1K + eacs 9K ~ 76KB
// -> 2 WGs/CU. POOL=1 on the final layer writes means to Pm (no race).
// ---------------------------------------------------------------------------
template <int POOL>
__global__ __launch_bounds__(256, 2) void k_fused(
    float* __restrict__ Xp, const float* __restrict__ W,
    const float* __restrict__ bcl, const float* __restrict__ gcl,
    const float* __restrict__ ccl,
    const int* __restrict__ ea_idx, const int* __restrict__ adj,
    const float* __restrict__ emb_ea, float* __restrict__ Pm) {
  int g = blockIdx.x >> 2, oct = blockIdx.x & 3;
  int tid = threadIdx.x;
  int lane = tid & 63, wv = tid >> 6;
  int x = lane & 15, quad = lane >> 4;

  __shared__ __align__(16) unsigned char u_raw[49152];
  unsigned* Xs = (unsigned*)u_raw;             // [256p][32k-swz] packed pairs
  unsigned* Ws = (unsigned*)(u_raw + 32768);   // [128h][32k-swz] packed pairs
  float*    Ys = (float*)u_raw;                // msg phase: [32hrel][8i][36k]
  __shared__ __align__(16) float aw_s[4][32 * 36];
  __shared__ unsigned char c8[1024];
  __shared__ float eacs[128 * 18];

  // ---- stage A-codes and eacs (used only after barriers in phase C)
  {
    int4 ev = ((const int4*)(ea_idx + (size_t)g * 1024))[tid];
    int4 av = ((const int4*)(adj   + (size_t)g * 1024))[tid];
    uchar4 c;
    c.x = av.x ? (unsigned char)ev.x : (unsigned char)16;
    c.y = av.y ? (unsigned char)ev.y : (unsigned char)16;
    c.z = av.z ? (unsigned char)ev.z : (unsigned char)16;
    c.w = av.w ? (unsigned char)ev.w : (unsigned char)16;
    ((uchar4*)c8)[tid] = c;
  }
#pragma unroll
  for (int it = 0; it < 8; it++) {
    int idx = it * 256 + tid;
    int e = idx >> 7, h = idx & 127;
    eacs[h * 18 + e] = emb_ea[e * 128 + h];
  }
  if (tid < 128) eacs[tid * 18 + 16] = 0.f;

  // ---- phase A: mlp (v4 verbatim; qb -> oct)
  f32x4 acc[4][8];
#pragma unroll
  for (int hh = 0; hh < 8; hh++) {
    float4 b4 = *(const float4*)(bcl + hh * 16 + quad * 4);
    f32x4 bi; bi[0] = b4.x; bi[1] = b4.y; bi[2] = b4.z; bi[3] = b4.w;
#pragma unroll
    for (int pt = 0; pt < 4; pt++) acc[pt][hh] = bi;
  }
  const float* Xg = Xp + ((size_t)g << 17) + oct * 256;

  for (int c = 0; c < 4; c++) {
    __syncthreads();
    {
      unsigned pk[8][4];
#pragma unroll
      for (int m = 0; m < 8; m++) {
        float4 v = *(const float4*)(Xg + (size_t)(c * 32 + wv * 8 + m) * 1024 + lane * 4);
        pk[m][0] = packf16(v.x); pk[m][1] = packf16(v.y);
        pk[m][2] = packf16(v.z); pk[m][3] = packf16(v.w);
      }
#pragma unroll
      for (int r = 0; r < 4; r++) {
        int p = 4 * lane + r;
        int sw = (p >> 2) & 7;
#pragma unroll
        for (int B2 = 0; B2 < 2; B2++) {
          int B = wv * 2 + B2;
          uint4 q4;
          q4.x = pk[B2 * 4 + 0][r]; q4.y = pk[B2 * 4 + 1][r];
          q4.z = pk[B2 * 4 + 2][r]; q4.w = pk[B2 * 4 + 3][r];
          *(uint4*)&Xs[p * 32 + ((B ^ sw) << 2)] = q4;
        }
      }
    }
    {
#pragma unroll
      for (int m = 0; m < 4; m++) {
        int f4 = m * 64 + lane;
        int kk = wv * 8 + (f4 >> 5);
        int h4 = (f4 & 31) * 4;
        float4 v = *(const float4*)(W + (size_t)(c * 32 + kk) * 128 + h4);
        int Bk = kk >> 2, km = kk & 3;
#pragma unroll
        for (int j = 0; j < 4; j++) {
          float vv = j == 0 ? v.x : (j == 1 ? v.y : (j == 2 ? v.z : v.w));
          int h = h4 + j;
          Ws[h * 32 + (((Bk ^ ((h >> 2) & 7)) << 2) + km)] = packf16(vv);
        }
      }
    }
    __syncthreads();
    H8 bh[4], bl[4];
#pragma unroll
    for (int pt = 0; pt < 4; pt++) {
      int p = wv * 64 + pt * 16 + x;
      int sw = (p >> 2) & 7;
#pragma unroll
      for (int n = 0; n < 4; n++) {
        int k = quad * 8 + n * 2;
        uint2 d = *(const uint2*)&Xs[p * 32 + (((k >> 2) ^ sw) << 2) + (k & 3)];
        bh[pt].u[n] = __builtin_amdgcn_perm(d.y, d.x, 0x05040100u);
        bl[pt].u[n] = __builtin_amdgcn_perm(d.y, d.x, 0x07060302u);
      }
    }
#pragma unroll
    for (int hh = 0; hh < 8; hh++) {
      H8 ah, al;
      int hrow = hh * 16 + x;
      int sw = (hrow >> 2) & 7;
#pragma unroll
      for (int n = 0; n < 4; n++) {
        int k = quad * 8 + n * 2;
        uint2 d = *(const uint2*)&Ws[hrow * 32 + (((k >> 2) ^ sw) << 2) + (k & 3)];
        ah.u[n] = __builtin_amdgcn_perm(d.y, d.x, 0x05040100u);
        al.u[n] = __builtin_amdgcn_perm(d.y, d.x, 0x07060302u);
      }
#pragma unroll
      for (int pt = 0; pt < 4; pt++) {
        acc[pt][hh] = __builtin_amdgcn_mfma_f32_16x16x32_f16(ah.v, bh[pt].v, acc[pt][hh], 0, 0, 0);
        acc[pt][hh] = __builtin_amdgcn_mfma_f32_16x16x32_f16(ah.v, bl[pt].v, acc[pt][hh], 0, 0, 0);
        acc[pt][hh] = __builtin_amdgcn_mfma_f32_16x16x32_f16(al.v, bh[pt].v, acc[pt][hh], 0, 0, 0);
      }
    }
  }

  // ---- phase B: LN + relu in registers (acc := Y)
  {
    float gm[4], gr[4];
#pragma unroll
    for (int pt = 0; pt < 4; pt++) {
      float s = 0.f;
#pragma unroll
      for (int hh = 0; hh < 8; hh++)
#pragma unroll
        for (int r = 0; r < 4; r++) s += acc[pt][hh][r];
      s += __shfl_xor(s, 16);
      s += __shfl_xor(s, 32);
      float m = s * (1.f / 128.f);
      float qv = 0.f;
#pragma unroll
      for (int hh = 0; hh < 8; hh++)
#pragma unroll
        for (int r = 0; r < 4; r++) { float d = acc[pt][hh][r] - m; qv += d * d; }
      qv += __shfl_xor(qv, 16);
      qv += __shfl_xor(qv, 32);
      gm[pt] = m;
      gr[pt] = rsqrtf(qv * (1.f / 128.f) + 1e-5f);
    }
#pragma unroll
    for (int hh = 0; hh < 8; hh++) {
      float4 g4 = *(const float4*)(gcl + hh * 16 + quad * 4);
      float4 c4 = *(const float4*)(ccl + hh * 16 + quad * 4);
      float ga[4] = {g4.x, g4.y, g4.z, g4.w};
      float ca[4] = {c4.x, c4.y, c4.z, c4.w};
#pragma unroll
      for (int r = 0; r < 4; r++)
#pragma unroll
        for (int pt = 0; pt < 4; pt++)
          acc[pt][hh][r] = fmaxf((acc[pt][hh][r] - gm[pt]) * gr[pt] * ga[r] + ca[r], 0.f);
    }
  }

  // ---- phase C: 4 rounds of 32 planes (deposit Y quarter + msg)
  int i_l = lane >> 3, j0 = (lane & 7) * 4;
  float* aw = aw_s[wv];
#pragma unroll
  for (int q = 0; q < 4; q++) {
    __syncthreads();   // Ys region free (staging done / prev round reads done)
#pragma unroll
    for (int hq = 0; hq < 2; hq++) {
      int hh = q * 2 + hq;
#pragma unroll
      for (int pt = 0; pt < 4; pt++) {
        int p_local = wv * 64 + pt * 16 + x;
        int il = p_local >> 5, kk = p_local & 31;
        float* dst = &Ys[(hq * 16 + quad * 4) * 292 + il * 36 + kk];
#pragma unroll
        for (int r = 0; r < 4; r++) dst[r * 292] = acc[pt][hh][r];
      }
    }
    __syncthreads();
    // msg: wave wv handles planes hrel = wv*8 .. +8 of this quarter
#pragma unroll 1
    for (int pl = 0; pl < 8; pl++) {
      int hrel = wv * 8 + pl;
      int h = q * 32 + hrel;
#pragma unroll
      for (int m = 0; m < 4; m++) {
        int qd = lane + 64 * m;
        uchar4 cc = ((const uchar4*)c8)[qd];
        float4 a;
        a.x = eacs[h * 18 + cc.x]; a.y = eacs[h * 18 + cc.y];
        a.z = eacs[h * 18 + cc.z]; a.w = eacs[h * 18 + cc.w];
        *(float4*)&aw[(qd >> 3) * 36 + (qd & 7) * 4] = a;
      }
      const float* yrow = &Ys[hrel * 292 + i_l * 36];
      float4 s = {0.f, 0.f, 0.f, 0.f};
#pragma unroll
      for (int kb = 0; kb < 8; kb++) {
        int k4 = kb * 4;
        float4 yv = *(const float4*)(yrow + k4);
        float4 b0 = *(const float4*)&aw[(k4 + 0) * 36 + j0];
        float4 b1 = *(const float4*)&aw[(k4 + 1) * 36 + j0];
        float4 b2 = *(const float4*)&aw[(k4 + 2) * 36 + j0];
        float4 b3 = *(const float4*)&aw[(k4 + 3) * 36 + j0];
        s.x += yv.x * b0.x; s.y += yv.x * b0.y; s.z += yv.x * b0.z; s.w += yv.x * b0.w;
        s.x += yv.y * b1.x; s.y += yv.y * b1.y; s.z += yv.y * b1.z; s.w += yv.y * b1.w;
        s.x += yv.z * b2.x; s.y += yv.z * b2.y; s.z += yv.z * b2.z; s.w += yv.z * b2.w;
        s.x += yv.w * b3.x; s.y += yv.w * b3.y; s.z += yv.w * b3.z; s.w += yv.w * b3.w;
      }
      float* xr = Xp + (((size_t)(g * 128 + h)) << 10) + (oct * 8 + i_l) * 32 + j0;
      float4 xv = *(const float4*)xr;
      xv.x += s.x; xv.y += s.y; xv.z += s.z; xv.w += s.w;
      if (!POOL) {
        *(float4*)xr = xv;
      } else {
        float sm = xv.x + xv.y + xv.z + xv.w;
        sm += __shfl_xor(sm, 1); sm += __shfl_xor(sm, 2); sm += __shfl_xor(sm, 4);
        if ((lane & 7) == 0)
          Pm[(size_t)g * 4096 + h * 32 + oct * 8 + i_l] = sm * 0.03125f;
      }
    }
  }
}

// ---------------------------------------------------------------------------
// T v3: reads pooled means from Pm[g][h][i] (written by k_fused<1>).
// -> @Wp+bp -> rowLN(registers+shfl) -> relu -> sum over i -> @Wq1+bq1 ->
// LN(wave reduce) -> relu -> @Wq2+bq2.
// ---------------------------------------------------------------------------
__global__ __launch_bounds__(256) void k_tail(
    const float* __restrict__ Pm,
    const float* __restrict__ Wp, const float* __restrict__ bp,
    const float* __restrict__ gp, const float* __restrict__ cp,
    const float* __restrict__ Wq1, const float* __restrict__ bq1,
    const float* __restrict__ gq1, const float* __restrict__ cq1,
    const float* __restrict__ Wq2, const float* __restrict__ bq2,
    float* __restrict__ out) {
  int g = blockIdx.x, tid = threadIdx.x;
  __shared__ float xs_s[32 * 132];
  __shared__ float y_s[32 * 132];
  __shared__ float stat_m[1], stat_r[1];
  __shared__ float hg_s[128];
  __shared__ float q_s[128];
  __shared__ float redf[128];
  const float* Pg = Pm + (size_t)g * 4096;
  {
    // load pooled means: Pg[h*32 + i] -> xs_s[i*132 + h]
    int h = tid >> 1, i0 = (tid & 1) * 16;
    const float4* src = (const float4*)(Pg + h * 32 + i0);
    float4 v0 = src[0], v1 = src[1], v2 = src[2], v3 = src[3];
    xs_s[(i0 +  0) * 132 + h] = v0.x; xs_s[(i0 +  1) * 132 + h] = v0.y;
    xs_s[(i0 +  2) * 132 + h] = v0.z; xs_s[(i0 +  3) * 132 + h] = v0.w;
    xs_s[(i0 +  4) * 132 + h] = v1.x; xs_s[(i0 +  5) * 132 + h] = v1.y;
    xs_s[(i0 +  6) * 132 + h] = v1.z; xs_s[(i0 +  7) * 132 + h] = v1.w;
    xs_s[(i0 +  8) * 132 + h] = v2.x; xs_s[(i0 +  9) * 132 + h] = v2.y;
    xs_s[(i0 + 10) * 132 + h] = v2.z; xs_s[(i0 + 11) * 132 + h] = v2.w;
    xs_s[(i0 + 12) * 132 + h] = v3.x; xs_s[(i0 + 13) * 132 + h] = v3.y;
    xs_s[(i0 + 14) * 132 + h] = v3.z; xs_s[(i0 + 15) * 132 + h] = v3.w;
  }
  __syncthreads();
  int i_ = tid >> 3, h0 = (tid & 7) * 16;
  float acc[16];
#pragma unroll
  for (int hh = 0; hh < 16; hh++) acc[hh] = bp[h0 + hh];
  for (int k = 0; k < 128; k++) {
    float a = xs_s[i_ * 132 + k];
    const float4* wr = (const float4*)(Wp + k * 128 + h0);
    float4 w0 = wr[0], w1 = wr[1], w2 = wr[2], w3 = wr[3];
    acc[0]  += a * w0.x; acc[1]  += a * w0.y; acc[2]  += a * w0.z; acc[3]  += a * w0.w;
    acc[4]  += a * w1.x; acc[5]  += a * w1.y; acc[6]  += a * w1.z; acc[7]  += a * w1.w;
    acc[8]  += a * w2.x; acc[9]  += a * w2.y; acc[10] += a * w2.z; acc[11] += a * w2.w;
    acc[12] += a * w3.x; acc[13] += a * w3.y; acc[14] += a * w3.z; acc[15] += a * w3.w;
  }
  {
    float s = 0.f;
#pragma unroll
    for (int hh = 0; hh < 16; hh++) s += acc[hh];
    s += __shfl_xor(s, 1); s += __shfl_xor(s, 2); s += __shfl_xor(s, 4);
    float m = s * (1.f / 128.f);
    float qv = 0.f;
#pragma unroll
    for (int hh = 0; hh < 16; hh++) { float d = acc[hh] - m; qv += d * d; }
    qv += __shfl_xor(qv, 1); qv += __shfl_xor(qv, 2); qv += __shfl_xor(qv, 4);
    float r = rsqrtf(qv * (1.f / 128.f) + 1e-5f);
#pragma unroll
    for (int hh = 0; hh < 16; hh++) {
      int hc = h0 + hh;
      float v = (acc[hh] - m) * r * gp[hc] + cp[hc];
      y_s[i_ * 132 + hc] = fmaxf(v, 0.f);
    }
  }
  __syncthreads();
  if (tid < 128) {
    float s = 0.f;
#pragma unroll
    for (int ii = 0; ii < 32; ii++) s += y_s[ii * 132 + tid];
    hg_s[tid] = s;
  }
  __syncthreads();
  if (tid < 128) {
    float a = bq1[tid];
    for (int k = 0; k < 128; k++) a += hg_s[k] * Wq1[k * 128 + tid];
    q_s[tid] = a;
  }
  __syncthreads();
  if (tid < 64) {
    float a = q_s[tid], b = q_s[tid + 64];
    float s = a + b;
#pragma unroll
    for (int o = 1; o < 64; o <<= 1) s += __shfl_xor(s, o);
    float m = s * (1.f / 128.f);
    float d1 = a - m, d2 = b - m;
    float qq = d1 * d1 + d2 * d2;
#pragma unroll
    for (int o = 1; o < 64; o <<= 1) qq += __shfl_xor(qq, o);
    if (tid == 0) { stat_m[0] = m; stat_r[0] = rsqrtf(qq * (1.f / 128.f) + 1e-5f); }
  }
  __syncthreads();
  if (tid < 128) {
    float v = (q_s[tid] - stat_m[0]) * stat_r[0] * gq1[tid] + cq1[tid];
    v = fmaxf(v, 0.f);
    redf[tid] = v * Wq2[tid];
  }
  __syncthreads();
  if (tid < 64) {
    float s = redf[tid] + redf[tid + 64];
#pragma unroll
    for (int o = 1; o < 64; o <<= 1) s += __shfl_xor(s, o);
    if (tid == 0) out[g] = s + bq2[0];
  }
}

// ---------------------------------------------------------------------------
extern "C" void kernel_launch(void* const* d_in, const int* in_sizes, int n_in,
                              void* d_out, int out_size, void* d_ws, size_t ws_size,
                              hipStream_t stream) {
  const int*   x_idx  = (const int*)d_in[0];
  const int*   ea_idx = (const int*)d_in[1];
  const int*   tf_idx = (const int*)d_in[2];
  const int*   adj    = (const int*)d_in[3];
  const float* emb_x  = (const float*)d_in[4];
  const float* emb_ea = (const float*)d_in[5];
  const float* emb_tf = (const float*)d_in[6];
  const float* W0  = (const float*)d_in[7];
  const float* b0  = (const float*)d_in[8];
  const float* W1  = (const float*)d_in[9];
  const float* b1  = (const float*)d_in[10];
  const float* Wc  = (const float*)d_in[11];
  const float* bc  = (const float*)d_in[12];
  const float* gc  = (const float*)d_in[13];
  const float* cc  = (const float*)d_in[14];
  const float* Wp  = (const float*)d_in[15];
  const float* bp  = (const float*)d_in[16];
  const float* gp  = (const float*)d_in[17];
  const float* cp  = (const float*)d_in[18];
  const float* Wq1 = (const float*)d_in[19];
  const float* bq1 = (const float*)d_in[20];
  const float* gq1 = (const float*)d_in[21];
  const float* cq1 = (const float*)d_in[22];
  const float* Wq2 = (const float*)d_in[23];
  const float* bq2 = (const float*)d_in[24];
  float* out = (float*)d_out;

  float* ws = (float*)d_ws;
  float* Xp = ws;
  float* Pm = ws + (size_t)16777216;
  float* P0 = ws + (size_t)33554432;
  float* P1 = P0 + 4096;

  k_emb_mm<<<2, 256, 0, stream>>>(emb_x, W0, b0, P0, W1, b1, P1);
  k_buildX<<<G, 256, 0, stream>>>(x_idx, tf_idx, P0, P1, emb_tf, Xp);
  for (int l = 0; l < L; l++) {
    if (l == L - 1)
      k_fused<1><<<G * 4, 256, 0, stream>>>(Xp, Wc + (size_t)l * H * H,
                                            bc + l * H, gc + l * H, cc + l * H,
                                            ea_idx, adj, emb_ea, Pm);
    else
      k_fused<0><<<G * 4, 256, 0, stream>>>(Xp, Wc + (size_t)l * H * H,
                                            bc + l * H, gc + l * H, cc + l * H,
                                            ea_idx, adj, emb_ea, Pm);
  }
  k_tail<<<G, 256, 0, stream>>>(Pm, Wp, bp, gp, cp, Wq1, bq1, gq1, cq1, Wq2, bq2, out);
}